// Round 20
// baseline (109.457 us; speedup 1.0000x reference)
//
#include <hip/hip_runtime.h>
#include <hip/hip_bf16.h>
#include <math.h>

#define SEQ 2048
#define DIM 1024
#define NH 16
#define FDIM 16
#define QKS 2560   // q/k buffer row stride: linQ@0 linK@256 winQ@512 winK@1536

typedef __bf16 bf16x8 __attribute__((ext_vector_type(8)));
typedef float f32x4 __attribute__((ext_vector_type(4)));
typedef __hip_bfloat16 bf16g;

__device__ __forceinline__ void gld16(const void* g, void* l) {
    __builtin_amdgcn_global_load_lds((const __attribute__((address_space(1))) void*)g,
                                     (__attribute__((address_space(3))) void*)l, 16, 0, 0);
}

// ---- 256-thread stagers: 16B-chunk XOR swizzle ----
__device__ __forceinline__ void stage128(char* lds, const bf16g* src, int stride, int tid) {
#pragma unroll
    for (int c = 0; c < 4; ++c) {
        const int idx = ((tid >> 6) * 256) + c * 64 + (tid & 63);
        const int row = idx >> 3, gg = idx & 7;
        gld16(src + (size_t)row * stride + ((gg ^ (row & 7)) * 8), lds + idx * 16);
    }
}
__device__ __forceinline__ void stage64_256(char* lds, const bf16g* src, int stride, int tid) {
#pragma unroll
    for (int c = 0; c < 2; ++c) {
        const int idx = ((tid >> 6) * 128) + c * 64 + (tid & 63);
        const int row = idx >> 3, gg = idx & 7;
        gld16(src + (size_t)row * stride + ((gg ^ (row & 7)) * 8),
              lds + (((tid >> 6) * 128) + c * 64) * 16);
    }
}

__device__ __forceinline__ bf16x8 frag64(const char* lds, int row, int kbase) {
    const int ch = kbase >> 3;
    return *(const bf16x8*)(lds + row * 128 + ((ch ^ (row & 7)) << 4));
}
__device__ __forceinline__ bf16x8 frag32(const char* lds, int row, int kbase) {
    const int ch = kbase >> 3;
    return *(const bf16x8*)(lds + row * 64 + ((ch ^ (row & 3)) << 4));
}

// ------------------- fused prep: convert_h + 8 weight transposes ------------
struct PrepArgs {
    const float* h; bf16g* h_b; const int* amask; float* bias;
    const float* src[8]; bf16g* dst[8]; int C[8]; int os[8];
};
__global__ __launch_bounds__(256) void prep_all(PrepArgs a) {
    const int tid = threadIdx.x;
    if (blockIdx.z == 0) {
        const int bid = blockIdx.x + blockIdx.y * 32;
        const size_t base = ((size_t)bid * 256 + tid) * 8;
        float4 v0 = *(const float4*)(a.h + base);
        float4 v1 = *(const float4*)(a.h + base + 4);
        __attribute__((aligned(16))) bf16g t[8];
        t[0] = __float2bfloat16(v0.x); t[1] = __float2bfloat16(v0.y);
        t[2] = __float2bfloat16(v0.z); t[3] = __float2bfloat16(v0.w);
        t[4] = __float2bfloat16(v1.x); t[5] = __float2bfloat16(v1.y);
        t[6] = __float2bfloat16(v1.z); t[7] = __float2bfloat16(v1.w);
        *(uint4*)(a.h_b + base) = *(const uint4*)t;
        const int tg = bid * 256 + tid;
        if (tg < SEQ) a.bias[tg] = (a.amask[tg] != 0) ? -3.0f : -1e30f;   // -3 softmax shift
        return;
    }
    const int j = blockIdx.z - 1;
    const int C = a.C[j];
    const int bc = blockIdx.x * 32;
    if (bc >= C) return;
    __shared__ float T[32][33];
    const float* in = a.src[j];
    bf16g* out = a.dst[j];
    const int os = a.os[j];
    const int br = blockIdx.y * 32;
    const int r = tid >> 3, c4 = (tid & 7) * 4;
    float4 v = *(const float4*)(in + (size_t)(br + r) * C + bc + c4);
    T[r][c4 + 0] = v.x; T[r][c4 + 1] = v.y; T[r][c4 + 2] = v.z; T[r][c4 + 3] = v.w;
    __syncthreads();
    const int c = tid >> 3, r4 = (tid & 7) * 4;
    __attribute__((aligned(8))) bf16g o[4];
#pragma unroll
    for (int i = 0; i < 4; ++i) o[i] = __float2bfloat16(T[r4 + i][c]);
    *(ushort4*)(out + (size_t)(bc + c) * os + br + r4) = *(const ushort4*)o;
}

// ------------------- bf16 MFMA GEMM body (2-phase dbuf, NREP n-frags) -------
template <int MODE, int NREP>
__device__ __forceinline__ void gemm_body(const bf16g* __restrict__ A,
                                          const bf16g* __restrict__ BT,
                                          float* __restrict__ Cf, bf16g* __restrict__ Cb,
                                          int N, int K, int bm, int bn,
                                          char* As0, char* As1, char* Bs0, char* Bs1) {
    const int tid = threadIdx.x, lane = tid & 63, w = tid >> 6;
    const int wr = (w >> 1) * 64, wc = (w & 1) * (NREP * 16);
    const int l15 = lane & 15, l4 = lane >> 4;
    f32x4 z = {0.f, 0.f, 0.f, 0.f};
    f32x4 acc[4][NREP];
#pragma unroll
    for (int m = 0; m < 4; ++m)
#pragma unroll
        for (int n = 0; n < NREP; ++n) acc[m][n] = z;

    stage128(As0, A + (size_t)bm * K, K, tid);
    if (NREP == 4) stage128(Bs0, BT + (size_t)bn * K, K, tid);
    else           stage64_256(Bs0, BT + (size_t)bn * K, K, tid);
    __syncthreads();
    int cur = 0;
    for (int k0 = 0; k0 < K; k0 += 64) {
        char* Asc = cur ? As1 : As0;
        char* Bsc = cur ? Bs1 : Bs0;
        if (k0 + 64 < K) {
            stage128(cur ? As0 : As1, A + (size_t)bm * K + k0 + 64, K, tid);
            if (NREP == 4) stage128(cur ? Bs0 : Bs1, BT + (size_t)bn * K + k0 + 64, K, tid);
            else           stage64_256(cur ? Bs0 : Bs1, BT + (size_t)bn * K + k0 + 64, K, tid);
        }
#pragma unroll
        for (int kk = 0; kk < 2; ++kk) {
            const int kb = kk * 32 + l4 * 8;
            bf16x8 a[4], b[NREP];
#pragma unroll
            for (int m = 0; m < 4; ++m) a[m] = frag64(Asc, wr + m * 16 + l15, kb);
#pragma unroll
            for (int n = 0; n < NREP; ++n) b[n] = frag64(Bsc, wc + n * 16 + l15, kb);
#pragma unroll
            for (int m = 0; m < 4; ++m)
#pragma unroll
                for (int n = 0; n < NREP; ++n)
                    acc[m][n] = __builtin_amdgcn_mfma_f32_16x16x32_bf16(a[m], b[n], acc[m][n], 0, 0, 0);
        }
        __syncthreads();
        cur ^= 1;
    }
#pragma unroll
    for (int m = 0; m < 4; ++m)
#pragma unroll
        for (int n = 0; n < NREP; ++n)
#pragma unroll
            for (int r = 0; r < 4; ++r) {
                const size_t off = (size_t)(bm + wr + m * 16 + l4 * 4 + r) * N + bn + wc + n * 16 + l15;
                if (MODE == 0) Cb[off] = __float2bfloat16(acc[m][n][r]);
                else Cf[off] = acc[m][n][r];
            }
}

// output GEMM: 128x64 tile -> 256 blocks (full CU coverage)
__global__ __launch_bounds__(256) void gemm_out(const bf16g* __restrict__ A,
                                                const bf16g* __restrict__ BT,
                                                float* __restrict__ Cf,
                                                int N, int K) {
    __shared__ char As[2][16384];
    __shared__ char Bs[2][8192];
    gemm_body<1, 2>(A, BT, Cf, nullptr, N, K, blockIdx.y * 128, blockIdx.x * 64,
                    As[0], As[1], Bs[0], Bs[1]);
}

// dual projection GEMM, 128x64 tiles (48KB LDS -> 3 blocks/CU):
// z=0 -> qkb = h_b @ BTqk^T (x<40) ; z=1 -> vT = WvT @ h_b^T (x<32)
__global__ __launch_bounds__(256) void gemm_dual(const bf16g* __restrict__ h_b,
                                                 const bf16g* __restrict__ BTqk,
                                                 const bf16g* __restrict__ WvT,
                                                 bf16g* __restrict__ qkb,
                                                 bf16g* __restrict__ vT) {
    __shared__ char As[2][16384];
    __shared__ char Bs[2][8192];
    if (blockIdx.z == 0) {
        gemm_body<0, 2>(h_b, BTqk, nullptr, qkb, QKS, DIM, blockIdx.y * 128, blockIdx.x * 64,
                        As[0], As[1], Bs[0], Bs[1]);
    } else {
        if (blockIdx.x >= SEQ / 64) return;
        gemm_body<0, 2>(WvT, h_b, nullptr, vT, SEQ, DIM, blockIdx.y * 128, blockIdx.x * 64,
                        As[0], As[1], Bs[0], Bs[1]);
    }
}

// ------------------- fused attention: 4 waves, 64 q-rows/block --------------
// Swapped QK^T: s = mfma(K_frag, Q_frag) -> q = C-col (l15, fixed/lane).
// Scalar per-lane denominator + shfl reduce; no rowsum MFMA; no setprio.
// LDS (40KB): K dbuf @0, V dbuf @16384+cur*8192, P @32768 + w*2048.
__global__ __launch_bounds__(256) void attn_fused(const bf16g* __restrict__ qk,
                                                  const bf16g* __restrict__ vT,
                                                  const float* __restrict__ bias,
                                                  bf16g* __restrict__ att) {
    __shared__ char L[40960];
    const int tid = threadIdx.x, lane = tid & 63, w = tid >> 6;
    const int bid = blockIdx.x;
    const int h = ((bid >> 3) & 1) * 8 + (bid & 7);
    const int rem = bid >> 4;
    const int branch = rem & 1;
    const int qt = 31 - (rem >> 1);   // heavy-first
    const int l15 = lane & 15, l4 = lane >> 4;
    char* Pw = L + 32768 + w * 2048;

    const f32x4 zero4 = {0.f, 0.f, 0.f, 0.f};
    f32x4 acc[4];
    float den = 0.f;
#pragma unroll
    for (int n = 0; n < 4; ++n) acc[n] = zero4;
    const int qrow = qt * 64 + w * 16 + l15;    // this lane's q (QK C-col AND Q-frag row)
    const int sgBase = qt * 64 + w * 16 + l4 * 4;
    const int pwCh0 = (l4 >> 1);
    char* PwBase = Pw + l15 * 128 + (l4 & 1) * 8;
    const int pXor = (l15 & 7);

    if (branch == 0) {
        // ---------------- win branch ----------------
        const bf16g* Kp = qk + 1536 + h * 64;
        const bf16g* Vp = vT + (size_t)(1024 + h * 64) * SEQ;
        const bf16g* Qr = qk + (size_t)qrow * QKS + 512 + h * 64;
        const bf16x8 aq0 = *(const bf16x8*)(Qr + l4 * 8);
        const bf16x8 aq1 = *(const bf16x8*)(Qr + 32 + l4 * 8);

        stage64_256(L, Kp, QKS, tid);
        stage64_256(L + 16384, Vp, SEQ, tid);
        __syncthreads();
        const int ktEnd = min(31, (qt * 64 + 286) >> 6);
        const int maskStart = qt + 4;
        int cur = 0;
        for (int kt = 0; kt <= ktEnd; ++kt) {
            const int kOff = cur * 8192;
            const int vOff = 16384 + cur * 8192;
            if (kt < ktEnd) {
                stage64_256(L + ((cur ^ 1) * 8192), Kp + (size_t)((kt + 1) * 64) * QKS, QKS, tid);
                stage64_256(L + (16384 + (cur ^ 1) * 8192), Vp + (kt + 1) * 64, SEQ, tid);
            }
            f32x4 s[4];
#pragma unroll
            for (int n = 0; n < 4; ++n) {
                f32x4 t = __builtin_amdgcn_mfma_f32_16x16x32_bf16(
                    frag64(L + kOff, n * 16 + l15, l4 * 8), aq0, zero4, 0, 0, 0);
                s[n] = __builtin_amdgcn_mfma_f32_16x16x32_bf16(
                    frag64(L + kOff, n * 16 + l15, 32 + l4 * 8), aq1, t, 0, 0, 0);
            }
            const bool needMask = (kt >= maskStart);
#pragma unroll
            for (int n = 0; n < 4; ++n) {
                const f32x4 b4 = *(const f32x4*)(bias + kt * 64 + n * 16 + l4 * 4);
                __attribute__((aligned(8))) bf16g pk[4];
#pragma unroll
                for (int r = 0; r < 4; ++r) {
                    float sc = fmaf(s[n][r], 0.125f, b4[r]);
                    if (needMask) {
                        const int tg = kt * 64 + n * 16 + l4 * 4 + r;
                        if (tg > qrow + 255) sc = -1e30f;
                    }
                    const float p = __expf(sc);
                    den += p;
                    pk[r] = __float2bfloat16(p);
                }
                const int ch = 2 * n + pwCh0;
                *(ushort4*)(PwBase + ((ch ^ pXor) << 4)) = *(const ushort4*)pk;
            }
#pragma unroll
            for (int kk = 0; kk < 2; ++kk) {
                bf16x8 pa = frag64(Pw, l15, kk * 32 + l4 * 8);
#pragma unroll
                for (int n = 0; n < 4; ++n)
                    acc[n] = __builtin_amdgcn_mfma_f32_16x16x32_bf16(
                        pa, frag64(L + vOff, n * 16 + l15, kk * 32 + l4 * 8), acc[n], 0, 0, 0);
            }
            __syncthreads();
            cur ^= 1;
        }
        // full denominator for q=l15: sum across l4 group (lanes stride 16)
        den += __shfl_xor(den, 16);
        den += __shfl_xor(den, 32);
        // redistribute den from (q=l15) to (q=l4*4+r) via wave-private LDS
        if (l4 == 0) *(float*)(Pw + l15 * 4) = den;
        f32x4 dq = *(const f32x4*)(Pw + l4 * 16);
#pragma unroll
        for (int n = 0; n < 4; ++n)
#pragma unroll
            for (int r = 0; r < 4; ++r) {
                const int sg = sgBase + r;
                att[(size_t)sg * 2048 + 1024 + h * 64 + n * 16 + l15] =
                    __float2bfloat16(acc[n][r] / dq[r]);
            }
    } else {
        // ---------------- lin branch ----------------
        const bf16g* Kp = qk + 256 + h * FDIM;
        const bf16g* Vp = vT + (size_t)(h * 64) * SEQ;
        const bf16x8 zf = {};
        const bf16x8 aq = (l4 < 2)
            ? *(const bf16x8*)(qk + (size_t)qrow * QKS + h * FDIM + l4 * 8) : zf;

        const uint4 z4 = {0u, 0u, 0u, 0u};
        {   // K [64][32]: 256 chunks
            const int row = tid >> 2, gp = tid & 3, g = gp ^ (row & 3);
            uint4 kv = (g < 2) ? *(const uint4*)(Kp + (size_t)row * QKS + g * 8) : z4;
            *(uint4*)(L + row * 64 + gp * 16) = kv;
        }
        stage64_256(L + 16384, Vp, SEQ, tid);
        __syncthreads();
        const int ktEnd = qt;
        int cur = 0;
        for (int kt = 0; kt <= ktEnd; ++kt) {
            const int kOff = cur * 4096;
            const int vOff = 16384 + cur * 8192;
            uint4 knext = z4;
            const int row = tid >> 2, gp = tid & 3, g = gp ^ (row & 3);
            if (kt < ktEnd) {
                if (g < 2)
                    knext = *(const uint4*)(Kp + (size_t)((kt + 1) * 64 + row) * QKS + g * 8);
                stage64_256(L + (16384 + (cur ^ 1) * 8192), Vp + (kt + 1) * 64, SEQ, tid);
            }
            f32x4 s[4];
#pragma unroll
            for (int n = 0; n < 4; ++n)
                s[n] = __builtin_amdgcn_mfma_f32_16x16x32_bf16(
                    frag32(L + kOff, n * 16 + l15, l4 * 8), aq, zero4, 0, 0, 0);
            const bool needMask = (kt == ktEnd);
#pragma unroll
            for (int n = 0; n < 4; ++n) {
                __attribute__((aligned(8))) bf16g pk[4];
#pragma unroll
                for (int r = 0; r < 4; ++r) {
                    const float d = s[n][r];
                    float sc = fmaf(d, fmaf(d, 1.f / 32.f, 0.25f), 1.f);
                    if (needMask) {
                        const int tg = kt * 64 + n * 16 + l4 * 4 + r;
                        if (tg > qrow) sc = 0.f;
                    }
                    den += sc;
                    pk[r] = __float2bfloat16(sc);
                }
                const int ch = 2 * n + pwCh0;
                *(ushort4*)(PwBase + ((ch ^ pXor) << 4)) = *(const ushort4*)pk;
            }
#pragma unroll
            for (int kk = 0; kk < 2; ++kk) {
                bf16x8 pa = frag64(Pw, l15, kk * 32 + l4 * 8);
#pragma unroll
                for (int n = 0; n < 4; ++n)
                    acc[n] = __builtin_amdgcn_mfma_f32_16x16x32_bf16(
                        pa, frag64(L + vOff, n * 16 + l15, kk * 32 + l4 * 8), acc[n], 0, 0, 0);
            }
            if (kt < ktEnd)
                *(uint4*)(L + ((cur ^ 1) * 4096) + row * 64 + gp * 16) = knext;
            __syncthreads();
            cur ^= 1;
        }
        den += __shfl_xor(den, 16);
        den += __shfl_xor(den, 32);
        if (l4 == 0) *(float*)(Pw + l15 * 4) = den;
        f32x4 dq = *(const f32x4*)(Pw + l4 * 16);
#pragma unroll
        for (int n = 0; n < 4; ++n)
#pragma unroll
            for (int r = 0; r < 4; ++r) {
                const int sg = sgBase + r;
                att[(size_t)sg * 2048 + h * 64 + n * 16 + l15] =
                    __float2bfloat16(acc[n][r] / (dq[r] + 1e-9f));
            }
    }
}

// ------------------- host -------------------
extern "C" void kernel_launch(void* const* d_in, const int* in_sizes, int n_in,
                              void* d_out, int out_size, void* d_ws, size_t ws_size,
                              hipStream_t stream) {
    const float* h      = (const float*)d_in[0];
    const int*   amask  = (const int*)d_in[1];
    const float* lin_Wq = (const float*)d_in[2];
    const float* lin_Wk = (const float*)d_in[3];
    const float* lin_Wv = (const float*)d_in[4];
    const float* lin_Wo = (const float*)d_in[5];
    const float* win_Wq = (const float*)d_in[6];
    const float* win_Wk = (const float*)d_in[7];
    const float* win_Wv = (const float*)d_in[8];
    const float* win_Wo = (const float*)d_in[9];
    float* out = (float*)d_out;

    char* p = (char*)d_ws;
    bf16g* h_b   = (bf16g*)p; p += (size_t)SEQ * DIM * 2;
    bf16g* BTqk  = (bf16g*)p; p += (size_t)QKS * DIM * 2;    // [2560][1024]
    bf16g* WvT   = (bf16g*)p; p += (size_t)2048 * DIM * 2;   // [linV^T; winV^T]
    bf16g* WoT   = (bf16g*)p; p += (size_t)DIM * 2048 * 2;
    bf16g* qkb   = (bf16g*)p; p += (size_t)SEQ * QKS * 2;    // [2048][2560]
    bf16g* vT    = (bf16g*)p; p += (size_t)2048 * SEQ * 2;   // [2048][2048]
    bf16g* att   = (bf16g*)p; p += (size_t)SEQ * 2048 * 2;
    float* bias  = (float*)p; p += (size_t)SEQ * 4;

    const dim3 blk(256);

    PrepArgs pa;
    pa.h = h; pa.h_b = h_b; pa.amask = amask; pa.bias = bias;
    pa.src[0] = lin_Wq; pa.dst[0] = BTqk;                      pa.C[0] = 256;  pa.os[0] = DIM;
    pa.src[1] = lin_Wk; pa.dst[1] = BTqk + (size_t)256 * DIM;  pa.C[1] = 256;  pa.os[1] = DIM;
    pa.src[2] = win_Wq; pa.dst[2] = BTqk + (size_t)512 * DIM;  pa.C[2] = 1024; pa.os[2] = DIM;
    pa.src[3] = win_Wk; pa.dst[3] = BTqk + (size_t)1536 * DIM; pa.C[3] = 1024; pa.os[3] = DIM;
    pa.src[4] = lin_Wv; pa.dst[4] = WvT;                       pa.C[4] = 1024; pa.os[4] = DIM;
    pa.src[5] = win_Wv; pa.dst[5] = WvT + (size_t)1024 * DIM;  pa.C[5] = 1024; pa.os[5] = DIM;
    pa.src[6] = lin_Wo; pa.dst[6] = WoT;                       pa.C[6] = 1024; pa.os[6] = 2048;
    pa.src[7] = win_Wo; pa.dst[7] = WoT + 1024;                pa.C[7] = 1024; pa.os[7] = 2048;
    prep_all<<<dim3(32, 32, 9), blk, 0, stream>>>(pa);

    // dual projection GEMM, 128x64 tiles: z=0 qkb (x<40); z=1 vT (x<32)
    gemm_dual<<<dim3(QKS / 64, 16, 2), blk, 0, stream>>>(h_b, BTqk, WvT, qkb, vT);

    attn_fused<<<dim3(2 * SEQ / 64 * NH), blk, 0, stream>>>(qkb, vT, bias, att);

    // output GEMM: 128x64 tile -> 16x16 = 256 blocks (full CU coverage)
    gemm_out<<<dim3(1024 / 64, SEQ / 128), blk, 0, stream>>>(att, WoT, out, DIM, 2048);
}

// Round 21
// 106.362 us; speedup vs baseline: 1.0291x; 1.0291x over previous
//
#include <hip/hip_runtime.h>
#include <hip/hip_bf16.h>
#include <math.h>

#define SEQ 2048
#define DIM 1024
#define NH 16
#define FDIM 16
#define QKS 2560   // q/k buffer row stride: linQ@0 linK@256 winQ@512 winK@1536

typedef __bf16 bf16x8 __attribute__((ext_vector_type(8)));
typedef float f32x4 __attribute__((ext_vector_type(4)));
typedef __hip_bfloat16 bf16g;

__device__ __forceinline__ void gld16(const void* g, void* l) {
    __builtin_amdgcn_global_load_lds((const __attribute__((address_space(1))) void*)g,
                                     (__attribute__((address_space(3))) void*)l, 16, 0, 0);
}

// ---- 256-thread stagers: 16B-chunk XOR swizzle ----
__device__ __forceinline__ void stage128(char* lds, const bf16g* src, int stride, int tid) {
#pragma unroll
    for (int c = 0; c < 4; ++c) {
        const int idx = ((tid >> 6) * 256) + c * 64 + (tid & 63);
        const int row = idx >> 3, gg = idx & 7;
        gld16(src + (size_t)row * stride + ((gg ^ (row & 7)) * 8), lds + idx * 16);
    }
}
__device__ __forceinline__ void stage64_256(char* lds, const bf16g* src, int stride, int tid) {
#pragma unroll
    for (int c = 0; c < 2; ++c) {
        const int idx = ((tid >> 6) * 128) + c * 64 + (tid & 63);
        const int row = idx >> 3, gg = idx & 7;
        gld16(src + (size_t)row * stride + ((gg ^ (row & 7)) * 8),
              lds + (((tid >> 6) * 128) + c * 64) * 16);
    }
}

__device__ __forceinline__ bf16x8 frag64(const char* lds, int row, int kbase) {
    const int ch = kbase >> 3;
    return *(const bf16x8*)(lds + row * 128 + ((ch ^ (row & 7)) << 4));
}
__device__ __forceinline__ bf16x8 frag32(const char* lds, int row, int kbase) {
    const int ch = kbase >> 3;
    return *(const bf16x8*)(lds + row * 64 + ((ch ^ (row & 3)) << 4));
}

// ------------------- fused prep: convert_h + 8 weight transposes ------------
struct PrepArgs {
    const float* h; bf16g* h_b; const int* amask; float* bias;
    const float* src[8]; bf16g* dst[8]; int C[8]; int os[8];
};
__global__ __launch_bounds__(256) void prep_all(PrepArgs a) {
    const int tid = threadIdx.x;
    if (blockIdx.z == 0) {
        const int bid = blockIdx.x + blockIdx.y * 32;
        const size_t base = ((size_t)bid * 256 + tid) * 8;
        float4 v0 = *(const float4*)(a.h + base);
        float4 v1 = *(const float4*)(a.h + base + 4);
        __attribute__((aligned(16))) bf16g t[8];
        t[0] = __float2bfloat16(v0.x); t[1] = __float2bfloat16(v0.y);
        t[2] = __float2bfloat16(v0.z); t[3] = __float2bfloat16(v0.w);
        t[4] = __float2bfloat16(v1.x); t[5] = __float2bfloat16(v1.y);
        t[6] = __float2bfloat16(v1.z); t[7] = __float2bfloat16(v1.w);
        *(uint4*)(a.h_b + base) = *(const uint4*)t;
        const int tg = bid * 256 + tid;
        if (tg < SEQ) a.bias[tg] = (a.amask[tg] != 0) ? -3.0f : -1e30f;   // -3 softmax shift
        return;
    }
    const int j = blockIdx.z - 1;
    const int C = a.C[j];
    const int bc = blockIdx.x * 32;
    if (bc >= C) return;
    __shared__ float T[32][33];
    const float* in = a.src[j];
    bf16g* out = a.dst[j];
    const int os = a.os[j];
    const int br = blockIdx.y * 32;
    const int r = tid >> 3, c4 = (tid & 7) * 4;
    float4 v = *(const float4*)(in + (size_t)(br + r) * C + bc + c4);
    T[r][c4 + 0] = v.x; T[r][c4 + 1] = v.y; T[r][c4 + 2] = v.z; T[r][c4 + 3] = v.w;
    __syncthreads();
    const int c = tid >> 3, r4 = (tid & 7) * 4;
    __attribute__((aligned(8))) bf16g o[4];
#pragma unroll
    for (int i = 0; i < 4; ++i) o[i] = __float2bfloat16(T[r4 + i][c]);
    *(ushort4*)(out + (size_t)(bc + c) * os + br + r4) = *(const ushort4*)o;
}

// ------------------- bf16 MFMA GEMM body (2-phase dbuf, NREP n-frags) -------
template <int MODE, int NREP>
__device__ __forceinline__ void gemm_body(const bf16g* __restrict__ A,
                                          const bf16g* __restrict__ BT,
                                          float* __restrict__ Cf, bf16g* __restrict__ Cb,
                                          int N, int K, int bm, int bn,
                                          char* As0, char* As1, char* Bs0, char* Bs1) {
    const int tid = threadIdx.x, lane = tid & 63, w = tid >> 6;
    const int wr = (w >> 1) * 64, wc = (w & 1) * (NREP * 16);
    const int l15 = lane & 15, l4 = lane >> 4;
    f32x4 z = {0.f, 0.f, 0.f, 0.f};
    f32x4 acc[4][NREP];
#pragma unroll
    for (int m = 0; m < 4; ++m)
#pragma unroll
        for (int n = 0; n < NREP; ++n) acc[m][n] = z;

    stage128(As0, A + (size_t)bm * K, K, tid);
    if (NREP == 4) stage128(Bs0, BT + (size_t)bn * K, K, tid);
    else           stage64_256(Bs0, BT + (size_t)bn * K, K, tid);
    __syncthreads();
    int cur = 0;
    for (int k0 = 0; k0 < K; k0 += 64) {
        char* Asc = cur ? As1 : As0;
        char* Bsc = cur ? Bs1 : Bs0;
        if (k0 + 64 < K) {
            stage128(cur ? As0 : As1, A + (size_t)bm * K + k0 + 64, K, tid);
            if (NREP == 4) stage128(cur ? Bs0 : Bs1, BT + (size_t)bn * K + k0 + 64, K, tid);
            else           stage64_256(cur ? Bs0 : Bs1, BT + (size_t)bn * K + k0 + 64, K, tid);
        }
#pragma unroll
        for (int kk = 0; kk < 2; ++kk) {
            const int kb = kk * 32 + l4 * 8;
            bf16x8 a[4], b[NREP];
#pragma unroll
            for (int m = 0; m < 4; ++m) a[m] = frag64(Asc, wr + m * 16 + l15, kb);
#pragma unroll
            for (int n = 0; n < NREP; ++n) b[n] = frag64(Bsc, wc + n * 16 + l15, kb);
#pragma unroll
            for (int m = 0; m < 4; ++m)
#pragma unroll
                for (int n = 0; n < NREP; ++n)
                    acc[m][n] = __builtin_amdgcn_mfma_f32_16x16x32_bf16(a[m], b[n], acc[m][n], 0, 0, 0);
        }
        __syncthreads();
        cur ^= 1;
    }
#pragma unroll
    for (int m = 0; m < 4; ++m)
#pragma unroll
        for (int n = 0; n < NREP; ++n)
#pragma unroll
            for (int r = 0; r < 4; ++r) {
                const size_t off = (size_t)(bm + wr + m * 16 + l4 * 4 + r) * N + bn + wc + n * 16 + l15;
                if (MODE == 0) Cb[off] = __float2bfloat16(acc[m][n][r]);
                else Cf[off] = acc[m][n][r];
            }
}

// output GEMM: 128x64 tile -> 256 blocks (full CU coverage)
__global__ __launch_bounds__(256) void gemm_out(const bf16g* __restrict__ A,
                                                const bf16g* __restrict__ BT,
                                                float* __restrict__ Cf,
                                                int N, int K) {
    __shared__ char As[2][16384];
    __shared__ char Bs[2][8192];
    gemm_body<1, 2>(A, BT, Cf, nullptr, N, K, blockIdx.y * 128, blockIdx.x * 64,
                    As[0], As[1], Bs[0], Bs[1]);
}

// dual projection GEMM: z=0 -> qkb = h_b @ BTqk^T ; z=1 -> vT = WvT @ h_b^T
__global__ __launch_bounds__(256) void gemm_dual(const bf16g* __restrict__ h_b,
                                                 const bf16g* __restrict__ BTqk,
                                                 const bf16g* __restrict__ WvT,
                                                 bf16g* __restrict__ qkb,
                                                 bf16g* __restrict__ vT) {
    __shared__ char As[2][16384];
    __shared__ char Bs[2][16384];
    if (blockIdx.z == 0) {
        gemm_body<0, 4>(h_b, BTqk, nullptr, qkb, QKS, DIM, blockIdx.y * 128, blockIdx.x * 128,
                        As[0], As[1], Bs[0], Bs[1]);
    } else {
        if (blockIdx.x >= SEQ / 128) return;
        gemm_body<0, 4>(WvT, h_b, nullptr, vT, SEQ, DIM, blockIdx.y * 128, blockIdx.x * 128,
                        As[0], As[1], Bs[0], Bs[1]);
    }
}

// ------------------- fused attention: 4 waves, 64 q-rows/block --------------
// Swapped QK^T: s = mfma(K_frag, Q_frag) -> q = C-col (l15, fixed/lane).
// Scalar per-lane denominator + shfl reduce; no rowsum MFMA; no setprio.
// LDS (40KB): K dbuf @0, V dbuf @16384+cur*8192, P @32768 + w*2048.
__global__ __launch_bounds__(256) void attn_fused(const bf16g* __restrict__ qk,
                                                  const bf16g* __restrict__ vT,
                                                  const float* __restrict__ bias,
                                                  bf16g* __restrict__ att) {
    __shared__ char L[40960];
    const int tid = threadIdx.x, lane = tid & 63, w = tid >> 6;
    const int bid = blockIdx.x;
    const int h = ((bid >> 3) & 1) * 8 + (bid & 7);
    const int rem = bid >> 4;
    const int branch = rem & 1;
    const int qt = 31 - (rem >> 1);   // heavy-first
    const int l15 = lane & 15, l4 = lane >> 4;
    char* Pw = L + 32768 + w * 2048;

    const f32x4 zero4 = {0.f, 0.f, 0.f, 0.f};
    f32x4 acc[4];
    float den = 0.f;
#pragma unroll
    for (int n = 0; n < 4; ++n) acc[n] = zero4;
    const int qrow = qt * 64 + w * 16 + l15;    // this lane's q (QK C-col AND Q-frag row)
    const int sgBase = qt * 64 + w * 16 + l4 * 4;
    const int pwCh0 = (l4 >> 1);
    char* PwBase = Pw + l15 * 128 + (l4 & 1) * 8;
    const int pXor = (l15 & 7);

    if (branch == 0) {
        // ---------------- win branch ----------------
        const bf16g* Kp = qk + 1536 + h * 64;
        const bf16g* Vp = vT + (size_t)(1024 + h * 64) * SEQ;
        const bf16g* Qr = qk + (size_t)qrow * QKS + 512 + h * 64;
        const bf16x8 aq0 = *(const bf16x8*)(Qr + l4 * 8);
        const bf16x8 aq1 = *(const bf16x8*)(Qr + 32 + l4 * 8);

        stage64_256(L, Kp, QKS, tid);
        stage64_256(L + 16384, Vp, SEQ, tid);
        __syncthreads();
        const int ktEnd = min(31, (qt * 64 + 286) >> 6);
        const int maskStart = qt + 4;
        int cur = 0;
        for (int kt = 0; kt <= ktEnd; ++kt) {
            const int kOff = cur * 8192;
            const int vOff = 16384 + cur * 8192;
            if (kt < ktEnd) {
                stage64_256(L + ((cur ^ 1) * 8192), Kp + (size_t)((kt + 1) * 64) * QKS, QKS, tid);
                stage64_256(L + (16384 + (cur ^ 1) * 8192), Vp + (kt + 1) * 64, SEQ, tid);
            }
            f32x4 s[4];
#pragma unroll
            for (int n = 0; n < 4; ++n) {
                f32x4 t = __builtin_amdgcn_mfma_f32_16x16x32_bf16(
                    frag64(L + kOff, n * 16 + l15, l4 * 8), aq0, zero4, 0, 0, 0);
                s[n] = __builtin_amdgcn_mfma_f32_16x16x32_bf16(
                    frag64(L + kOff, n * 16 + l15, 32 + l4 * 8), aq1, t, 0, 0, 0);
            }
            const bool needMask = (kt >= maskStart);
#pragma unroll
            for (int n = 0; n < 4; ++n) {
                const f32x4 b4 = *(const f32x4*)(bias + kt * 64 + n * 16 + l4 * 4);
                __attribute__((aligned(8))) bf16g pk[4];
#pragma unroll
                for (int r = 0; r < 4; ++r) {
                    float sc = fmaf(s[n][r], 0.125f, b4[r]);
                    if (needMask) {
                        const int tg = kt * 64 + n * 16 + l4 * 4 + r;
                        if (tg > qrow + 255) sc = -1e30f;
                    }
                    const float p = __expf(sc);
                    den += p;
                    pk[r] = __float2bfloat16(p);
                }
                const int ch = 2 * n + pwCh0;
                *(ushort4*)(PwBase + ((ch ^ pXor) << 4)) = *(const ushort4*)pk;
            }
#pragma unroll
            for (int kk = 0; kk < 2; ++kk) {
                bf16x8 pa = frag64(Pw, l15, kk * 32 + l4 * 8);
#pragma unroll
                for (int n = 0; n < 4; ++n)
                    acc[n] = __builtin_amdgcn_mfma_f32_16x16x32_bf16(
                        pa, frag64(L + vOff, n * 16 + l15, kk * 32 + l4 * 8), acc[n], 0, 0, 0);
            }
            __syncthreads();
            cur ^= 1;
        }
        // full denominator for q=l15: sum across l4 group (lanes stride 16)
        den += __shfl_xor(den, 16);
        den += __shfl_xor(den, 32);
        // redistribute den from (q=l15) to (q=l4*4+r) via wave-private LDS
        if (l4 == 0) *(float*)(Pw + l15 * 4) = den;
        f32x4 dq = *(const f32x4*)(Pw + l4 * 16);
#pragma unroll
        for (int n = 0; n < 4; ++n)
#pragma unroll
            for (int r = 0; r < 4; ++r) {
                const int sg = sgBase + r;
                att[(size_t)sg * 2048 + 1024 + h * 64 + n * 16 + l15] =
                    __float2bfloat16(acc[n][r] / dq[r]);
            }
    } else {
        // ---------------- lin branch ----------------
        const bf16g* Kp = qk + 256 + h * FDIM;
        const bf16g* Vp = vT + (size_t)(h * 64) * SEQ;
        const bf16x8 zf = {};
        const bf16x8 aq = (l4 < 2)
            ? *(const bf16x8*)(qk + (size_t)qrow * QKS + h * FDIM + l4 * 8) : zf;

        const uint4 z4 = {0u, 0u, 0u, 0u};
        {   // K [64][32]: 256 chunks
            const int row = tid >> 2, gp = tid & 3, g = gp ^ (row & 3);
            uint4 kv = (g < 2) ? *(const uint4*)(Kp + (size_t)row * QKS + g * 8) : z4;
            *(uint4*)(L + row * 64 + gp * 16) = kv;
        }
        stage64_256(L + 16384, Vp, SEQ, tid);
        __syncthreads();
        const int ktEnd = qt;
        int cur = 0;
        for (int kt = 0; kt <= ktEnd; ++kt) {
            const int kOff = cur * 4096;
            const int vOff = 16384 + cur * 8192;
            uint4 knext = z4;
            const int row = tid >> 2, gp = tid & 3, g = gp ^ (row & 3);
            if (kt < ktEnd) {
                if (g < 2)
                    knext = *(const uint4*)(Kp + (size_t)((kt + 1) * 64 + row) * QKS + g * 8);
                stage64_256(L + (16384 + (cur ^ 1) * 8192), Vp + (kt + 1) * 64, SEQ, tid);
            }
            f32x4 s[4];
#pragma unroll
            for (int n = 0; n < 4; ++n)
                s[n] = __builtin_amdgcn_mfma_f32_16x16x32_bf16(
                    frag32(L + kOff, n * 16 + l15, l4 * 8), aq, zero4, 0, 0, 0);
            const bool needMask = (kt == ktEnd);
#pragma unroll
            for (int n = 0; n < 4; ++n) {
                __attribute__((aligned(8))) bf16g pk[4];
#pragma unroll
                for (int r = 0; r < 4; ++r) {
                    const float d = s[n][r];
                    float sc = fmaf(d, fmaf(d, 1.f / 32.f, 0.25f), 1.f);
                    if (needMask) {
                        const int tg = kt * 64 + n * 16 + l4 * 4 + r;
                        if (tg > qrow) sc = 0.f;
                    }
                    den += sc;
                    pk[r] = __float2bfloat16(sc);
                }
                const int ch = 2 * n + pwCh0;
                *(ushort4*)(PwBase + ((ch ^ pXor) << 4)) = *(const ushort4*)pk;
            }
#pragma unroll
            for (int kk = 0; kk < 2; ++kk) {
                bf16x8 pa = frag64(Pw, l15, kk * 32 + l4 * 8);
#pragma unroll
                for (int n = 0; n < 4; ++n)
                    acc[n] = __builtin_amdgcn_mfma_f32_16x16x32_bf16(
                        pa, frag64(L + vOff, n * 16 + l15, kk * 32 + l4 * 8), acc[n], 0, 0, 0);
            }
            if (kt < ktEnd)
                *(uint4*)(L + ((cur ^ 1) * 4096) + row * 64 + gp * 16) = knext;
            __syncthreads();
            cur ^= 1;
        }
        den += __shfl_xor(den, 16);
        den += __shfl_xor(den, 32);
        if (l4 == 0) *(float*)(Pw + l15 * 4) = den;
        f32x4 dq = *(const f32x4*)(Pw + l4 * 16);
#pragma unroll
        for (int n = 0; n < 4; ++n)
#pragma unroll
            for (int r = 0; r < 4; ++r) {
                const int sg = sgBase + r;
                att[(size_t)sg * 2048 + h * 64 + n * 16 + l15] =
                    __float2bfloat16(acc[n][r] / (dq[r] + 1e-9f));
            }
    }
}

// ------------------- host -------------------
extern "C" void kernel_launch(void* const* d_in, const int* in_sizes, int n_in,
                              void* d_out, int out_size, void* d_ws, size_t ws_size,
                              hipStream_t stream) {
    const float* h      = (const float*)d_in[0];
    const int*   amask  = (const int*)d_in[1];
    const float* lin_Wq = (const float*)d_in[2];
    const float* lin_Wk = (const float*)d_in[3];
    const float* lin_Wv = (const float*)d_in[4];
    const float* lin_Wo = (const float*)d_in[5];
    const float* win_Wq = (const float*)d_in[6];
    const float* win_Wk = (const float*)d_in[7];
    const float* win_Wv = (const float*)d_in[8];
    const float* win_Wo = (const float*)d_in[9];
    float* out = (float*)d_out;

    char* p = (char*)d_ws;
    bf16g* h_b   = (bf16g*)p; p += (size_t)SEQ * DIM * 2;
    bf16g* BTqk  = (bf16g*)p; p += (size_t)QKS * DIM * 2;    // [2560][1024]
    bf16g* WvT   = (bf16g*)p; p += (size_t)2048 * DIM * 2;   // [linV^T; winV^T]
    bf16g* WoT   = (bf16g*)p; p += (size_t)DIM * 2048 * 2;
    bf16g* qkb   = (bf16g*)p; p += (size_t)SEQ * QKS * 2;    // [2048][2560]
    bf16g* vT    = (bf16g*)p; p += (size_t)2048 * SEQ * 2;   // [2048][2048]
    bf16g* att   = (bf16g*)p; p += (size_t)SEQ * 2048 * 2;
    float* bias  = (float*)p; p += (size_t)SEQ * 4;

    const dim3 blk(256);

    PrepArgs pa;
    pa.h = h; pa.h_b = h_b; pa.amask = amask; pa.bias = bias;
    pa.src[0] = lin_Wq; pa.dst[0] = BTqk;                      pa.C[0] = 256;  pa.os[0] = DIM;
    pa.src[1] = lin_Wk; pa.dst[1] = BTqk + (size_t)256 * DIM;  pa.C[1] = 256;  pa.os[1] = DIM;
    pa.src[2] = win_Wq; pa.dst[2] = BTqk + (size_t)512 * DIM;  pa.C[2] = 1024; pa.os[2] = DIM;
    pa.src[3] = win_Wk; pa.dst[3] = BTqk + (size_t)1536 * DIM; pa.C[3] = 1024; pa.os[3] = DIM;
    pa.src[4] = lin_Wv; pa.dst[4] = WvT;                       pa.C[4] = 1024; pa.os[4] = DIM;
    pa.src[5] = win_Wv; pa.dst[5] = WvT + (size_t)1024 * DIM;  pa.C[5] = 1024; pa.os[5] = DIM;
    pa.src[6] = lin_Wo; pa.dst[6] = WoT;                       pa.C[6] = 1024; pa.os[6] = 2048;
    pa.src[7] = win_Wo; pa.dst[7] = WoT + 1024;                pa.C[7] = 1024; pa.os[7] = 2048;
    prep_all<<<dim3(32, 32, 9), blk, 0, stream>>>(pa);

    // dual projection GEMM: z=0 qkb [2048][2560]; z=1 vT [2048][2048]
    gemm_dual<<<dim3(QKS / 128, 16, 2), blk, 0, stream>>>(h_b, BTqk, WvT, qkb, vT);

    attn_fused<<<dim3(2 * SEQ / 64 * NH), blk, 0, stream>>>(qkb, vT, bias, att);

    // output GEMM: 128x64 tile -> 16x16 = 256 blocks (full CU coverage)
    gemm_out<<<dim3(1024 / 64, SEQ / 128), blk, 0, stream>>>(att, WoT, out, DIM, 2048);
}